// Round 14
// baseline (505.234 us; speedup 1.0000x reference)
//
#include <hip/hip_runtime.h>
#include <hip/hip_bf16.h>
#include <cstdint>

#define N_NODES 20000
#define E_EDGES 320000
#define P_TYPES 4
#define HEADS   8
#define DHID    256
#define NCLASSES 16
#define NEG_SLOPE 0.2f
#define PE_TOT (P_TYPES * E_EDGES)
#define PN_TOT (P_TYPES * N_NODES)
#define NCHUNK 32                     // chunks per edge type (10000 edges each)
#define CH_E   10000                  // edges per chunk

typedef __attribute__((ext_vector_type(8))) short bf16x8;
typedef __attribute__((ext_vector_type(8))) unsigned short ushort8;
typedef __attribute__((ext_vector_type(4))) float f32x4;
typedef __attribute__((ext_vector_type(4))) int i32x4;   // clang vector: ok for nontemporal builtins

static __device__ __forceinline__ unsigned short f2bf(float v) {
    __hip_bfloat16 h = __float2bfloat16(v);
    return *(unsigned short*)&h;
}
static __device__ __forceinline__ float bf2f(unsigned short u) {
    __hip_bfloat16 h = *(__hip_bfloat16*)&u;
    return __bfloat162float(h);
}
static __device__ __forceinline__ float fast_tanh(float x) {
    x = fminf(fmaxf(x, -10.f), 10.f);
    float t = __expf(2.f * x);
    return (t - 1.f) * __builtin_amdgcn_rcpf(t + 1.f);   // ~1e-6 rel, plenty
}
static __device__ __forceinline__ float u2f(unsigned u) { return __uint_as_float(u); }

// ===== prep: LDS-hist(+rank) || convert_x || convert_weights(+score zero) ===
// hist: 128 blocks = p(4) x chunk(32); each block scans its 10000 edges ONCE.
// All 20000 dst bins in LDS as packed 2x16-bit counters (40 KB). atomicAdd
// return gives per-edge rank (coalesced nt write). No global atomics.
__global__ __launch_bounds__(256)
void prep_kernel(const float* __restrict__ x, unsigned short* __restrict__ xh,
                 unsigned short* __restrict__ xl,
                 const float* __restrict__ Wp1, const float* __restrict__ Wp2,
                 const float* __restrict__ Wk1, const float* __restrict__ Wk2,
                 unsigned short* __restrict__ Wp1h, unsigned short* __restrict__ Wp1l,
                 unsigned short* __restrict__ Wp2h, unsigned short* __restrict__ Wp2l,
                 unsigned short* __restrict__ Wk1h, unsigned short* __restrict__ Wk2h,
                 float* __restrict__ score,
                 const int* __restrict__ edst, int* __restrict__ gHist,
                 int* __restrict__ rank)
{
    __shared__ unsigned lhist[N_NODES / 2];             // 10000 words = 40 KB
    int b = blockIdx.x;
    if (b < 128) {                                      // ---- LDS hist + rank ----
        int p = b >> 5, c = b & 31;
        for (int s = threadIdx.x; s < N_NODES / 2; s += 256) lhist[s] = 0u;
        __syncthreads();
        int base = p * E_EDGES + c * CH_E;
        #pragma unroll 4
        for (int it = 0; it < 40; it++) {
            int o = it * 256 + threadIdx.x;
            if (o < CH_E) {
                int e = base + o;
                int d = edst[e];
                int sh = (d & 1) << 4;
                unsigned old = atomicAdd(&lhist[d >> 1], 1u << sh);
                __builtin_nontemporal_store((int)((old >> sh) & 0xffffu), &rank[e]);
            }
        }
        __syncthreads();
        for (int s = threadIdx.x; s < N_NODES; s += 256) {
            int cnt = (int)((lhist[s >> 1] >> ((s & 1) << 4)) & 0xffffu);
            __builtin_nontemporal_store(cnt, &gHist[(p * N_NODES + s) * NCHUNK + c]);
        }
    } else if (b < 10128) {                             // x -> hi/lo bf16 (exact)
        int idx = (b - 128) * 256 + threadIdx.x;
        float4 v = ((const float4*)x)[idx];
        ushort4 h, l;
        h.x = f2bf(v.x); h.y = f2bf(v.y); h.z = f2bf(v.z); h.w = f2bf(v.w);
        l.x = f2bf(v.x - bf2f(h.x)); l.y = f2bf(v.y - bf2f(h.y));
        l.z = f2bf(v.z - bf2f(h.z)); l.w = f2bf(v.w - bf2f(h.w));
        ((ushort4*)xh)[idx] = h;
        ((ushort4*)xl)[idx] = l;
    } else {                                            // weights -> k-tiled bf16
        int id = (b - 10128) * 256 + threadIdx.x;
        if (id < 8) score[id] = 0.f;
        if (id < 131072) {                              // Wp1, K=512
            int n = id & 255, k = id >> 8;
            float v = Wp1[id];
            unsigned short h = f2bf(v);
            size_t dst = ((size_t)(k >> 5) * 256 + n) * 32 + (k & 31);
            Wp1h[dst] = h; Wp1l[dst] = f2bf(v - bf2f(h));
        } else if (id < 196608) {                       // Wp2, K=256
            int i2 = id - 131072;
            int n = i2 & 255, k = i2 >> 8;
            float v = Wp2[i2];
            unsigned short h = f2bf(v);
            size_t dst = ((size_t)(k >> 5) * 256 + n) * 32 + (k & 31);
            Wp2h[dst] = h; Wp2l[dst] = f2bf(v - bf2f(h));
        } else if (id < 262144) {                       // Wk1 hi
            int i2 = id - 196608;
            int n = i2 & 255, k = i2 >> 8;
            size_t dst = ((size_t)(k >> 5) * 256 + n) * 32 + (k & 31);
            Wk1h[dst] = f2bf(Wk1[i2]);
        } else if (id < 327680) {                       // Wk2 hi
            int i2 = id - 262144;
            int n = i2 & 255, k = i2 >> 8;
            size_t dst = ((size_t)(k >> 5) * 256 + n) * 32 + (k & 31);
            Wk2h[dst] = f2bf(Wk2[i2]);
        }
    }
}

// ========== proj GEMM + atomic-free CSR fill riding along ====================
__global__ __launch_bounds__(256)
void proj_fill(const unsigned short* __restrict__ Ah, const unsigned short* __restrict__ Al,
               const unsigned short* __restrict__ BgH, const unsigned short* __restrict__ BgL,
               const float* __restrict__ bias, const float* __restrict__ att_s,
               const float* __restrict__ att_d, unsigned short* __restrict__ zb,
               float* __restrict__ a_s, float* __restrict__ a_d, int M, int K,
               int projBlocks, const int* __restrict__ chunkOff,
               const int* __restrict__ rank, const int* __restrict__ edst,
               const int* __restrict__ esrc, int* __restrict__ csr_src)
{
    __shared__ int4 smem[1920];                         // 30 KB (proj AS+BS)
    int4* AS = smem;                                    // 640 int4
    int4* BS = smem + 640;                              // 1280 int4

    if ((int)blockIdx.x >= projBlocks) {                // ---- CSR fill path ----
        int base = (blockIdx.x - projBlocks) * 512 + threadIdx.x;
        #pragma unroll
        for (int t = 0; t < 2; t++) {
            int e = base + t * 256;                     // exact: 2500*512 == PE_TOT
            int p = e / E_EDGES;
            int o = e - p * E_EDGES;
            int c = o / CH_E;
            int d = edst[e];
            int pos = chunkOff[(p * N_NODES + d) * NCHUNK + c] + rank[e];
            __builtin_nontemporal_store(esrc[e], &csr_src[pos]);
        }
        return;
    }

    const int bx = blockIdx.x >> 1, by = blockIdx.x & 1;
    const int row0 = bx * 64;
    const int tid = threadIdx.x, lane = tid & 63, w = tid >> 6;

    f32x4 acc[4][2];
    const f32x4 zero4 = {0.f, 0.f, 0.f, 0.f};
    #pragma unroll
    for (int i = 0; i < 4; i++) { acc[i][0] = zero4; acc[i][1] = zero4; }

    for (int k0 = 0; k0 < K; k0 += 32) {
        {   // stage A: 64 rows x 32 k hi+lo (pure copies)
            int r = tid >> 2, f = tid & 3;
            int rg_ = row0 + r;
            int4 vh = make_int4(0, 0, 0, 0), vl = make_int4(0, 0, 0, 0);
            if (rg_ < M) {
                size_t a = (size_t)rg_ * K + k0 + f * 8;
                vh = *(const int4*)&Ah[a];
                vl = *(const int4*)&Al[a];
            }
            AS[r * 5 + f] = vh;
            AS[64 * 5 + r * 5 + f] = vl;
        }
        {   // stage B: 128 n-rows x 32 k hi+lo from k-tiled layout (coalesced)
            size_t bbase = (size_t)(k0 >> 5) * (256 * 32) + (size_t)(by * 128) * 32;
            #pragma unroll
            for (int it = 0; it < 2; it++) {
                int id = tid + it * 256;
                int r = id >> 2, f = id & 3;
                size_t a = bbase + (size_t)r * 32 + f * 8;
                BS[r * 5 + f] = *(const int4*)&BgH[a];
                BS[128 * 5 + r * 5 + f] = *(const int4*)&BgL[a];
            }
        }
        __syncthreads();

        const bf16x8* ASv = (const bf16x8*)AS;
        const bf16x8* BSv = (const bf16x8*)BS;
        const int slot = lane >> 4;
        bf16x8 ah[4], al[4];
        #pragma unroll
        for (int mt = 0; mt < 4; mt++) {
            int r = mt * 16 + (lane & 15);
            ah[mt] = ASv[r * 5 + slot];
            al[mt] = ASv[64 * 5 + r * 5 + slot];
        }
        #pragma unroll
        for (int nt = 0; nt < 2; nt++) {
            int rb = (w * 2 + nt) * 16 + (lane & 15);
            bf16x8 bh = BSv[rb * 5 + slot];
            bf16x8 bl = BSv[128 * 5 + rb * 5 + slot];
            #pragma unroll
            for (int mt = 0; mt < 4; mt++) {
                acc[mt][nt] = __builtin_amdgcn_mfma_f32_16x16x32_bf16(ah[mt], bh, acc[mt][nt], 0, 0, 0);
                acc[mt][nt] = __builtin_amdgcn_mfma_f32_16x16x32_bf16(ah[mt], bl, acc[mt][nt], 0, 0, 0);
                acc[mt][nt] = __builtin_amdgcn_mfma_f32_16x16x32_bf16(al[mt], bh, acc[mt][nt], 0, 0, 0);
            }
        }
        __syncthreads();
    }

    // Epilogue. C/D: col=lane&15 within 16-tile, row=(lane>>4)*4+reg.
    const int c15 = lane & 15, lhi = lane >> 4;
    const int hd = by * 4 + w;
    float asw[2], adw[2], bw[2];
    #pragma unroll
    for (int nt = 0; nt < 2; nt++) {
        int col = by * 128 + w * 32 + nt * 16 + c15;
        asw[nt] = att_s[col]; adw[nt] = att_d[col]; bw[nt] = bias[col];
    }
    #pragma unroll
    for (int mt = 0; mt < 4; mt++) {
        #pragma unroll
        for (int rg = 0; rg < 4; rg++) {
            int row = row0 + mt * 16 + lhi * 4 + rg;
            bool ok = row < M;
            float v0 = acc[mt][0][rg] + bw[0], v1 = acc[mt][1][rg] + bw[1];
            if (ok) {
                unsigned short* zp = zb + (size_t)row * DHID + by * 128 + w * 32 + c15;
                zp[0] = f2bf(v0); zp[16] = f2bf(v1);
            }
            float hs = v0 * asw[0] + v1 * asw[1];
            float hdd = v0 * adw[0] + v1 * adw[1];
            #pragma unroll
            for (int off = 1; off < 16; off <<= 1) {
                hs += __shfl_xor(hs, off, 64); hdd += __shfl_xor(hdd, off, 64);
            }
            if (ok && c15 == 0) {
                a_s[row * HEADS + hd] = hs;
                a_d[row * HEADS + hd] = hdd;
            }
        }
    }
}

// ========== score GEMM: bf16 A (relu'd), K=256, score-reduce epilogue =======
__global__ __launch_bounds__(256)
void score_gemm(const unsigned short* __restrict__ Ab, const unsigned short* __restrict__ BgH,
                const float* __restrict__ bias, const float* __restrict__ q,
                float* __restrict__ score, int M)
{
    __shared__ int4 AS[64 * 5];
    __shared__ int4 BS[256 * 5];
    __shared__ float red[4][2];
    const int row0 = blockIdx.x * 64;
    const int tid = threadIdx.x, lane = tid & 63, w = tid >> 6;

    f32x4 acc[4][4];
    const f32x4 zero4 = {0.f, 0.f, 0.f, 0.f};
    #pragma unroll
    for (int i = 0; i < 4; i++)
        #pragma unroll
        for (int j = 0; j < 4; j++) acc[i][j] = zero4;

    for (int k0 = 0; k0 < 256; k0 += 32) {
        {   // stage A: bf16 copy + relu bit-trick
            int r = tid >> 2, f = tid & 3;
            union { int4 v; unsigned short u[8]; } t;
            t.v = *(const int4*)&Ab[(size_t)(row0 + r) * DHID + k0 + f * 8];
            #pragma unroll
            for (int j = 0; j < 8; j++) if (t.u[j] & 0x8000) t.u[j] = 0;
            AS[r * 5 + f] = t.v;
        }
        {   // stage B: k-tile [256][32] hi
            size_t bbase = (size_t)(k0 >> 5) * (256 * 32);
            #pragma unroll
            for (int it = 0; it < 4; it++) {
                int id = tid + it * 256;
                BS[(id >> 2) * 5 + (id & 3)] = *(const int4*)&BgH[bbase + (size_t)id * 8];
            }
        }
        __syncthreads();

        const bf16x8* ASv = (const bf16x8*)AS;
        const bf16x8* BSv = (const bf16x8*)BS;
        const int slot = lane >> 4;
        bf16x8 ah[4];
        #pragma unroll
        for (int mt = 0; mt < 4; mt++) ah[mt] = ASv[(mt * 16 + (lane & 15)) * 5 + slot];
        #pragma unroll
        for (int nt = 0; nt < 4; nt++) {
            bf16x8 bh = BSv[((w * 4 + nt) * 16 + (lane & 15)) * 5 + slot];
            #pragma unroll
            for (int mt = 0; mt < 4; mt++)
                acc[mt][nt] = __builtin_amdgcn_mfma_f32_16x16x32_bf16(ah[mt], bh, acc[mt][nt], 0, 0, 0);
        }
        __syncthreads();
    }

    const int pbase = row0 / N_NODES;
    const int rowSplit = (pbase + 1) * N_NODES;
    float l0 = 0.f, l1 = 0.f;
    #pragma unroll
    for (int nt = 0; nt < 4; nt++) {
        int col = (w * 4 + nt) * 16 + (lane & 15);
        float qc = q[col], bc = bias[col];
        #pragma unroll
        for (int mt = 0; mt < 4; mt++)
            #pragma unroll
            for (int rg = 0; rg < 4; rg++) {
                int row = row0 + mt * 16 + (lane >> 4) * 4 + rg;
                float v = qc * fast_tanh(acc[mt][nt][rg] + bc);
                if (row >= rowSplit) l1 += v; else l0 += v;
            }
    }
    #pragma unroll
    for (int off = 32; off > 0; off >>= 1) {
        l0 += __shfl_down(l0, off, 64);
        l1 += __shfl_down(l1, off, 64);
    }
    if (lane == 0) { red[w][0] = l0; red[w][1] = l1; }
    __syncthreads();
    if (tid == 0)
        atomicAdd(score + pbase, red[0][0] + red[1][0] + red[2][0] + red[3][0]);
    if (tid == 1 && pbase + 1 < P_TYPES)
        atomicAdd(score + pbase + 1, red[0][1] + red[1][1] + red[2][1] + red[3][1]);
}

// ================= scan: gHist -> chunkOff (2.56M entries) ==================
__global__ __launch_bounds__(1024)
void scan_block(const int* __restrict__ counts, int* __restrict__ out,
                int* __restrict__ blockSum, int total)
{
    __shared__ int wsum[16];
    int tid = threadIdx.x, lane = tid & 63, w = tid >> 6;
    int i = blockIdx.x * 1024 + tid;
    int v = (i < total) ? counts[i] : 0;
    int incl = v;
    #pragma unroll
    for (int off = 1; off < 64; off <<= 1) {
        int t = __shfl_up(incl, off, 64);
        if (lane >= off) incl += t;
    }
    if (lane == 63) wsum[w] = incl;
    __syncthreads();
    if (w == 0) {
        int s = (lane < 16) ? wsum[lane] : 0;
        #pragma unroll
        for (int off = 1; off < 16; off <<= 1) {
            int t = __shfl_up(s, off, 64);
            if (lane >= off) s += t;
        }
        if (lane < 16) wsum[lane] = s;
    }
    __syncthreads();
    int waveoff = w ? wsum[w - 1] : 0;
    if (i < total) out[i] = waveoff + incl - v;
    if (tid == 1023 && blockSum) blockSum[blockIdx.x] = wsum[15];
}

// single-block in-place exclusive scan with carry
__global__ __launch_bounds__(1024)
void scan_mid(int* __restrict__ data, int total)
{
    __shared__ int wsum[16];
    __shared__ int carry_s;
    int tid = threadIdx.x, lane = tid & 63, w = tid >> 6;
    if (tid == 0) carry_s = 0;
    __syncthreads();
    for (int base = 0; base < total; base += 1024) {
        int i = base + tid;
        int v = (i < total) ? data[i] : 0;
        int incl = v;
        #pragma unroll
        for (int off = 1; off < 64; off <<= 1) {
            int t = __shfl_up(incl, off, 64);
            if (lane >= off) incl += t;
        }
        if (lane == 63) wsum[w] = incl;
        __syncthreads();
        if (w == 0) {
            int s = (lane < 16) ? wsum[lane] : 0;
            #pragma unroll
            for (int off = 1; off < 16; off <<= 1) {
                int t = __shfl_up(s, off, 64);
                if (lane >= off) s += t;
            }
            if (lane < 16) wsum[lane] = s;
        }
        __syncthreads();
        int waveoff = w ? wsum[w - 1] : 0;
        int carry = carry_s;
        if (i < total) data[i] = carry + waveoff + incl - v;
        __syncthreads();
        if (tid == 1023) carry_s = carry + wsum[15];
        __syncthreads();
    }
}

// add block offsets; extract row_start (every NCHUNK-th) + sentinel
__global__ __launch_bounds__(1024)
void scan_add(int* __restrict__ chunkOff, const int* __restrict__ blockOff,
              int* __restrict__ row_start, int total)
{
    int i = blockIdx.x * 1024 + threadIdx.x;
    if (i == 0) row_start[PN_TOT] = PE_TOT;
    if (i < total) {
        int v = chunkOff[i] + blockOff[blockIdx.x];
        chunkOff[i] = v;
        if ((i & (NCHUNK - 1)) == 0) row_start[i / NCHUNK] = v;
    }
}

// ------- CSR gather: 1 wave/segment, 8 edges in flight, packed bf16 unpack --
__global__ __launch_bounds__(256)
void gather_kernel(const int* __restrict__ row_start, const int* __restrict__ csr_src,
                   const float* __restrict__ a_src, const float* __restrict__ a_dst,
                   const unsigned short* __restrict__ zb, unsigned short* __restrict__ outsb)
{
    int seg = blockIdx.x * 4 + (threadIdx.x >> 6);      // p*N + dst (grid exact)
    int lane = threadIdx.x & 63;
    int sub = lane >> 5, cl = lane & 31;
    int h = cl >> 2;
    int dst = seg % N_NODES;
    float ad = a_dst[dst * HEADS + h];
    int start = row_start[seg], end = row_start[seg + 1];

    float acc[8] = {};
    float den = 0.f;
    int i = start + sub;
    for (; i + 6 < end; i += 8) {                       // 4 edges per half-wave in flight
        int s0 = __builtin_nontemporal_load(&csr_src[i]);
        int s1 = __builtin_nontemporal_load(&csr_src[i + 2]);
        int s2 = __builtin_nontemporal_load(&csr_src[i + 4]);
        int s3 = __builtin_nontemporal_load(&csr_src[i + 6]);
        float g0 = a_src[s0 * HEADS + h];
        float g1 = a_src[s1 * HEADS + h];
        float g2 = a_src[s2 * HEADS + h];
        float g3 = a_src[s3 * HEADS + h];
        uint4 z0 = *(const uint4*)(zb + (size_t)s0 * DHID + cl * 8);
        uint4 z1 = *(const uint4*)(zb + (size_t)s1 * DHID + cl * 8);
        uint4 z2 = *(const uint4*)(zb + (size_t)s2 * DHID + cl * 8);
        uint4 z3 = *(const uint4*)(zb + (size_t)s3 * DHID + cl * 8);
        float e0 = g0 + ad; e0 = e0 > 0.f ? e0 : NEG_SLOPE * e0;
        float e1 = g1 + ad; e1 = e1 > 0.f ? e1 : NEG_SLOPE * e1;
        float e2 = g2 + ad; e2 = e2 > 0.f ? e2 : NEG_SLOPE * e2;
        float e3 = g3 + ad; e3 = e3 > 0.f ? e3 : NEG_SLOPE * e3;
        float w0 = __expf(e0), w1 = __expf(e1), w2 = __expf(e2), w3 = __expf(e3);
        acc[0] += w0 * u2f(z0.x << 16); acc[1] += w0 * u2f(z0.x & 0xffff0000u);
        acc[2] += w0 * u2f(z0.y << 16); acc[3] += w0 * u2f(z0.y & 0xffff0000u);
        acc[4] += w0 * u2f(z0.z << 16); acc[5] += w0 * u2f(z0.z & 0xffff0000u);
        acc[6] += w0 * u2f(z0.w << 16); acc[7] += w0 * u2f(z0.w & 0xffff0000u);
        acc[0] += w1 * u2f(z1.x << 16); acc[1] += w1 * u2f(z1.x & 0xffff0000u);
        acc[2] += w1 * u2f(z1.y << 16); acc[3] += w1 * u2f(z1.y & 0xffff0000u);
        acc[4] += w1 * u2f(z1.z << 16); acc[5] += w1 * u2f(z1.z & 0xffff0000u);
        acc[6] += w1 * u2f(z1.w << 16); acc[7] += w1 * u2f(z1.w & 0xffff0000u);
        acc[0] += w2 * u2f(z2.x << 16); acc[1] += w2 * u2f(z2.x & 0xffff0000u);
        acc[2] += w2 * u2f(z2.y << 16); acc[3] += w2 * u2f(z2.y & 0xffff0000u);
        acc[4] += w2 * u2f(z2.z << 16); acc[5] += w2 * u2f(z2.z & 0xffff0000u);
        acc[6] += w2 * u2f(z2.w << 16); acc[7] += w2 * u2f(z2.w & 0xffff0000u);
        acc[0] += w3 * u2f(z3.x << 16); acc[1] += w3 * u2f(z3.x & 0xffff0000u);
        acc[2] += w3 * u2f(z3.y << 16); acc[3] += w3 * u2f(z3.y & 0xffff0000u);
        acc[4] += w3 * u2f(z3.z << 16); acc[5] += w3 * u2f(z3.z & 0xffff0000u);
        acc[6] += w3 * u2f(z3.w << 16); acc[7] += w3 * u2f(z3.w & 0xffff0000u);
        den += (w0 + w1) + (w2 + w3);
    }
    for (; i < end; i += 2) {
        int s0 = csr_src[i];
        float g0 = a_src[s0 * HEADS + h];
        uint4 z0 = *(const uint4*)(zb + (size_t)s0 * DHID + cl * 8);
        float e0 = g0 + ad; e0 = e0 > 0.f ? e0 : NEG_SLOPE * e0;
        float w0 = __expf(e0);
        acc[0] += w0 * u2f(z0.x << 16); acc[1] += w0 * u2f(z0.x & 0xffff0000u);
        acc[2] += w0 * u2f(z0.y << 16); acc[3] += w0 * u2f(z0.y & 0xffff0000u);
        acc[4] += w0 * u2f(z0.z << 16); acc[5] += w0 * u2f(z0.z & 0xffff0000u);
        acc[6] += w0 * u2f(z0.w << 16); acc[7] += w0 * u2f(z0.w & 0xffff0000u);
        den += w0;
    }
    den += __shfl_xor(den, 32, 64);
    #pragma unroll
    for (int j = 0; j < 8; j++) acc[j] += __shfl_xor(acc[j], 32, 64);
    if (sub == 0) {
        float inv = den > 0.f ? 1.0f / den : 0.f;
        ushort8 o;
        #pragma unroll
        for (int j = 0; j < 8; j++) o[j] = f2bf(acc[j] * inv);
        __builtin_nontemporal_store(*(i32x4*)&o,
            (i32x4*)(outsb + (size_t)seg * DHID + cl * 8));
    }
}

// -------- weighted sum over types, fused beta softmax (+relu, opt elu) ------
// OUTMODE 0: fused final classifier -> out f32 [N,16] (block owns 8 rows).
// OUTMODE 1: write bf16 hi/lo (input for proj2).
template<int OUTMODE, bool ELU>
__global__ __launch_bounds__(256)
void wsum_kernel(const unsigned short* __restrict__ outsb, const float* __restrict__ score,
                 unsigned short* __restrict__ hh, unsigned short* __restrict__ hl,
                 const float* __restrict__ Wo, const float* __restrict__ bo,
                 float* __restrict__ out)
{
    __shared__ float hblk[8][256];                      // only used by OUTMODE 0
    int idx = blockIdx.x * 256 + threadIdx.x;           // ushort8 index into [N,256]
    float s0 = score[0], s1 = score[1], s2 = score[2], s3 = score[3];
    float m = fmaxf(fmaxf(s0, s1), fmaxf(s2, s3));
    float b[4];
    b[0] = __expf((s0 - m) * (1.f / N_NODES));
    b[1] = __expf((s1 - m) * (1.f / N_NODES));
    b[2] = __expf((s2 - m) * (1.f / N_NODES));
    b[3] = __expf((s3 - m) * (1.f / N_NODES));
    float dinv = 1.f / (b[0] + b[1] + b[2] + b[3]);
    b[0] *= dinv; b[1] *= dinv; b[2] *= dinv; b[3] *= dinv;

    const size_t stride = (size_t)N_NODES * DHID / 8;
    float r[8] = {};
    #pragma unroll
    for (int p = 0; p < 4; p++) {
        i32x4 t = __builtin_nontemporal_load(
            (const i32x4*)(outsb + (idx + p * stride) * 8));
        ushort8 v = *(ushort8*)&t;
        #pragma unroll
        for (int j = 0; j < 8; j++) r[j] += b[p] * fmaxf(bf2f(v[j]), 0.f);
    }
    if (ELU) {
        #pragma unroll
        for (int j = 0; j < 8; j++) r[j] = r[j] > 0.f ? r[j] : expm1f(r[j]);
    }
    if (OUTMODE == 1) {
        ushort8 vh, vl;
        #pragma unroll
        for (int j = 0; j < 8; j++) {
            vh[j] = f2bf(r[j]);
            vl[j] = f2bf(r[j] - bf2f(vh[j]));
        }
        ((ushort8*)hh)[idx] = vh;
        ((ushort8*)hl)[idx] = vl;
    } else {
        // stage this block's 8 rows, then 128 threads do [8x256]@[256x16]+bo
        int row_l = threadIdx.x >> 5, u = threadIdx.x & 31;
        #pragma unroll
        for (int j = 0; j < 8; j++) hblk[row_l][u * 8 + j] = r[j];
        __syncthreads();
        int j = threadIdx.x;
        if (j < 8 * NCLASSES) {
            int rl = j >> 4, c = j & 15;
            float accv = bo[c];
            const float* hr = hblk[rl];
            #pragma unroll 8
            for (int k = 0; k < DHID; k++) accv = fmaf(hr[k], Wo[k * NCLASSES + c], accv);
            out[(size_t)(blockIdx.x * 8 + rl) * NCLASSES + c] = accv;
        }
    }
}

extern "C" void kernel_launch(void* const* d_in, const int* in_sizes, int n_in,
                              void* d_out, int out_size, void* d_ws, size_t ws_size,
                              hipStream_t stream)
{
    const float* x   = (const float*)d_in[0];
    const int*  esrc = (const int*)d_in[1];
    const int*  edst = (const int*)d_in[2];
    const float* Wp1 = (const float*)d_in[3];
    const float* bp1 = (const float*)d_in[4];
    const float* as1 = (const float*)d_in[5];
    const float* ad1 = (const float*)d_in[6];
    const float* Wk1 = (const float*)d_in[7];
    const float* bk1 = (const float*)d_in[8];
    const float* q1  = (const float*)d_in[9];
    const float* Wp2 = (const float*)d_in[10];
    const float* bp2 = (const float*)d_in[11];
    const float* as2 = (const float*)d_in[12];
    const float* ad2 = (const float*)d_in[13];
    const float* Wk2 = (const float*)d_in[14];
    const float* bk2 = (const float*)d_in[15];
    const float* q2  = (const float*)d_in[16];
    const float* Wo  = (const float*)d_in[17];
    const float* bo  = (const float*)d_in[18];
    float* out = (float*)d_out;

    // workspace layout (byte offsets, all 16B-aligned)
    char* wsb = (char*)d_ws;
    int* gHist    = (int*)wsb;                                    // 10,240,000
    int* chunkOff = (int*)(wsb + 10240000);                       // 10,240,000
    float* a_s   = (float*)(wsb + 20480000);                      //    640,000
    float* a_d   = (float*)(wsb + 21120000);                      //    640,000
    float* score = (float*)(wsb + 21760000);                      //         32
    unsigned short* zb      = (unsigned short*)(wsb + 21760032);  // 10,240,000
    unsigned short* outsb   = (unsigned short*)(wsb + 32000032);  // 40,960,000
    unsigned short* x_hi    = (unsigned short*)(wsb + 72960032);  // 20,480,000
    unsigned short* x_lo    = (unsigned short*)(wsb + 93440032);  // 20,480,000
    unsigned short* h_hi    = (unsigned short*)(wsb + 113920032); // 10,240,000
    unsigned short* h_lo    = (unsigned short*)(wsb + 124160032); // 10,240,000
    int* rank = (int*)h_hi;   // aliases h_hi: rank lives prep->fill(L1), h_hi wsum(L1)->proj2
    unsigned short* Wp1t_hi = (unsigned short*)(wsb + 134400032); //    262,144
    unsigned short* Wp1t_lo = (unsigned short*)(wsb + 134662176);
    unsigned short* Wp2t_hi = (unsigned short*)(wsb + 134924320); //    131,072
    unsigned short* Wp2t_lo = (unsigned short*)(wsb + 135055392);
    unsigned short* Wk1t_hi = (unsigned short*)(wsb + 135186464);
    unsigned short* Wk2t_hi = (unsigned short*)(wsb + 135317536);
    int* row_start = (int*)(wsb + 135448608);                     //    320,016
    int* blockSum  = (int*)(wsb + 135768624);                     //     10,000
    int* csr_src   = (int*)(wsb + 136089648);                     //  5,120,000

    const int SCAN_TOT = PN_TOT * NCHUNK;        // 2,560,000
    const int NBS = SCAN_TOT / 1024;             // 2500 (exact)

    // ---- prep: {LDS-hist+rank || convert_x || convert_weights} ----
    prep_kernel<<<11408, 256, 0, stream>>>(x, x_hi, x_lo, Wp1, Wp2, Wk1, Wk2,
        Wp1t_hi, Wp1t_lo, Wp2t_hi, Wp2t_lo, Wk1t_hi, Wk2t_hi, score,
        edst, gHist, rank);

    // ---- scan: gHist -> chunkOff (exclusive) + row_start extraction ----
    scan_block<<<NBS, 1024, 0, stream>>>(gHist, chunkOff, blockSum, SCAN_TOT);
    scan_mid<<<1, 1024, 0, stream>>>(blockSum, NBS);
    scan_add<<<NBS, 1024, 0, stream>>>(chunkOff, blockSum, row_start, SCAN_TOT);

    const int PROJ_BLOCKS = 626;                 // 313 x 2
    const int FILL_BLOCKS = PE_TOT / 512;        // 2500 light blocks (exact)
    const int gw = N_NODES * DHID / 8 / 256;     // 2500 blocks, 8 rows each

    // ---- layer 1 (CSR fill rides along with proj1) ----
    proj_fill<<<PROJ_BLOCKS + FILL_BLOCKS, 256, 0, stream>>>(
        x_hi, x_lo, Wp1t_hi, Wp1t_lo, bp1, as1, ad1, zb, a_s, a_d, N_NODES, 512,
        PROJ_BLOCKS, chunkOff, rank, edst, esrc, csr_src);
    gather_kernel<<<PN_TOT / 4, 256, 0, stream>>>(row_start, csr_src, a_s, a_d, zb, outsb);
    score_gemm<<<PN_TOT / 64, 256, 0, stream>>>(outsb, Wk1t_hi, bk1, q1, score, PN_TOT);
    wsum_kernel<1, true><<<gw, 256, 0, stream>>>(outsb, score, h_hi, h_lo,
                                                 nullptr, nullptr, nullptr);

    // ---- layer 2 ----
    proj_fill<<<PROJ_BLOCKS, 256, 0, stream>>>(
        h_hi, h_lo, Wp2t_hi, Wp2t_lo, bp2, as2, ad2, zb, a_s, a_d, N_NODES, 256,
        PROJ_BLOCKS, chunkOff, rank, edst, esrc, csr_src);
    gather_kernel<<<PN_TOT / 4, 256, 0, stream>>>(row_start, csr_src, a_s, a_d, zb, outsb);
    score_gemm<<<PN_TOT / 64, 256, 0, stream>>>(outsb, Wk2t_hi, bk2, q2, score + 4, PN_TOT);
    wsum_kernel<0, false><<<gw, 256, 0, stream>>>(outsb, score + 4, nullptr, nullptr,
                                                  Wo, bo, out);
}

// Round 15
// 424.813 us; speedup vs baseline: 1.1893x; 1.1893x over previous
//
#include <hip/hip_runtime.h>
#include <hip/hip_bf16.h>
#include <cstdint>

#define N_NODES 20000
#define E_EDGES 320000
#define P_TYPES 4
#define HEADS   8
#define DHID    256
#define NCLASSES 16
#define NEG_SLOPE 0.2f
#define PE_TOT (P_TYPES * E_EDGES)
#define PN_TOT (P_TYPES * N_NODES)
#define NCHUNK 32                     // chunks per edge type (10000 edges each)
#define CH_E   10000                  // edges per chunk

typedef __attribute__((ext_vector_type(8))) short bf16x8;
typedef __attribute__((ext_vector_type(8))) unsigned short ushort8;
typedef __attribute__((ext_vector_type(4))) float f32x4;

static __device__ __forceinline__ unsigned short f2bf(float v) {
    __hip_bfloat16 h = __float2bfloat16(v);
    return *(unsigned short*)&h;
}
static __device__ __forceinline__ float bf2f(unsigned short u) {
    __hip_bfloat16 h = *(__hip_bfloat16*)&u;
    return __bfloat162float(h);
}
static __device__ __forceinline__ float fast_tanh(float x) {
    x = fminf(fmaxf(x, -10.f), 10.f);
    float t = __expf(2.f * x);
    return (t - 1.f) * __builtin_amdgcn_rcpf(t + 1.f);   // ~1e-6 rel, plenty
}
static __device__ __forceinline__ float u2f(unsigned u) { return __uint_as_float(u); }

// ===== prep: LDS-hist(+rank) || convert_x || convert_weights(+score zero) ===
// hist: 128 blocks = p(4) x chunk(32); each block scans its 10000 edges ONCE.
// All 20000 dst bins in LDS as packed 2x16-bit counters (40 KB). atomicAdd
// return gives per-edge rank (coalesced write). No global atomics.
__global__ __launch_bounds__(256)
void prep_kernel(const float* __restrict__ x, unsigned short* __restrict__ xh,
                 unsigned short* __restrict__ xl,
                 const float* __restrict__ Wp1, const float* __restrict__ Wp2,
                 const float* __restrict__ Wk1, const float* __restrict__ Wk2,
                 unsigned short* __restrict__ Wp1h, unsigned short* __restrict__ Wp1l,
                 unsigned short* __restrict__ Wp2h, unsigned short* __restrict__ Wp2l,
                 unsigned short* __restrict__ Wk1h, unsigned short* __restrict__ Wk2h,
                 float* __restrict__ score,
                 const int* __restrict__ edst, int* __restrict__ gHist,
                 int* __restrict__ rank)
{
    __shared__ unsigned lhist[N_NODES / 2];             // 10000 words = 40 KB
    int b = blockIdx.x;
    if (b < 128) {                                      // ---- LDS hist + rank ----
        int p = b >> 5, c = b & 31;
        for (int s = threadIdx.x; s < N_NODES / 2; s += 256) lhist[s] = 0u;
        __syncthreads();
        int base = p * E_EDGES + c * CH_E;
        #pragma unroll 4
        for (int it = 0; it < 40; it++) {
            int o = it * 256 + threadIdx.x;
            if (o < CH_E) {
                int e = base + o;
                int d = edst[e];
                int sh = (d & 1) << 4;
                unsigned old = atomicAdd(&lhist[d >> 1], 1u << sh);
                rank[e] = (int)((old >> sh) & 0xffffu);
            }
        }
        __syncthreads();
        for (int s = threadIdx.x; s < N_NODES; s += 256) {
            int cnt = (int)((lhist[s >> 1] >> ((s & 1) << 4)) & 0xffffu);
            gHist[(p * N_NODES + s) * NCHUNK + c] = cnt;
        }
    } else if (b < 10128) {                             // x -> hi/lo bf16 (exact)
        int idx = (b - 128) * 256 + threadIdx.x;
        float4 v = ((const float4*)x)[idx];
        ushort4 h, l;
        h.x = f2bf(v.x); h.y = f2bf(v.y); h.z = f2bf(v.z); h.w = f2bf(v.w);
        l.x = f2bf(v.x - bf2f(h.x)); l.y = f2bf(v.y - bf2f(h.y));
        l.z = f2bf(v.z - bf2f(h.z)); l.w = f2bf(v.w - bf2f(h.w));
        ((ushort4*)xh)[idx] = h;
        ((ushort4*)xl)[idx] = l;
    } else {                                            // weights -> k-tiled bf16
        int id = (b - 10128) * 256 + threadIdx.x;
        if (id < 8) score[id] = 0.f;
        if (id < 131072) {                              // Wp1, K=512
            int n = id & 255, k = id >> 8;
            float v = Wp1[id];
            unsigned short h = f2bf(v);
            size_t dst = ((size_t)(k >> 5) * 256 + n) * 32 + (k & 31);
            Wp1h[dst] = h; Wp1l[dst] = f2bf(v - bf2f(h));
        } else if (id < 196608) {                       // Wp2, K=256
            int i2 = id - 131072;
            int n = i2 & 255, k = i2 >> 8;
            float v = Wp2[i2];
            unsigned short h = f2bf(v);
            size_t dst = ((size_t)(k >> 5) * 256 + n) * 32 + (k & 31);
            Wp2h[dst] = h; Wp2l[dst] = f2bf(v - bf2f(h));
        } else if (id < 262144) {                       // Wk1 hi
            int i2 = id - 196608;
            int n = i2 & 255, k = i2 >> 8;
            size_t dst = ((size_t)(k >> 5) * 256 + n) * 32 + (k & 31);
            Wk1h[dst] = f2bf(Wk1[i2]);
        } else if (id < 327680) {                       // Wk2 hi
            int i2 = id - 262144;
            int n = i2 & 255, k = i2 >> 8;
            size_t dst = ((size_t)(k >> 5) * 256 + n) * 32 + (k & 31);
            Wk2h[dst] = f2bf(Wk2[i2]);
        }
    }
}

// ========== proj GEMM + atomic-free CSR fill riding along ====================
__global__ __launch_bounds__(256)
void proj_fill(const unsigned short* __restrict__ Ah, const unsigned short* __restrict__ Al,
               const unsigned short* __restrict__ BgH, const unsigned short* __restrict__ BgL,
               const float* __restrict__ bias, const float* __restrict__ att_s,
               const float* __restrict__ att_d, unsigned short* __restrict__ zb,
               float* __restrict__ a_s, float* __restrict__ a_d, int M, int K,
               int projBlocks, const int* __restrict__ chunkOff,
               const int* __restrict__ rank, const int* __restrict__ edst,
               const int* __restrict__ esrc, int* __restrict__ csr_src)
{
    __shared__ int4 smem[1920];                         // 30 KB (proj AS+BS)
    int4* AS = smem;                                    // 640 int4
    int4* BS = smem + 640;                              // 1280 int4

    if ((int)blockIdx.x >= projBlocks) {                // ---- CSR fill path ----
        int base = (blockIdx.x - projBlocks) * 512 + threadIdx.x;
        #pragma unroll
        for (int t = 0; t < 2; t++) {
            int e = base + t * 256;                     // exact: 2500*512 == PE_TOT
            int p = e / E_EDGES;
            int o = e - p * E_EDGES;
            int c = o / CH_E;
            int d = edst[e];
            csr_src[chunkOff[(p * N_NODES + d) * NCHUNK + c] + rank[e]] = esrc[e];
        }
        return;
    }

    const int bx = blockIdx.x >> 1, by = blockIdx.x & 1;
    const int row0 = bx * 64;
    const int tid = threadIdx.x, lane = tid & 63, w = tid >> 6;

    f32x4 acc[4][2];
    const f32x4 zero4 = {0.f, 0.f, 0.f, 0.f};
    #pragma unroll
    for (int i = 0; i < 4; i++) { acc[i][0] = zero4; acc[i][1] = zero4; }

    for (int k0 = 0; k0 < K; k0 += 32) {
        {   // stage A: 64 rows x 32 k hi+lo (pure copies)
            int r = tid >> 2, f = tid & 3;
            int rg_ = row0 + r;
            int4 vh = make_int4(0, 0, 0, 0), vl = make_int4(0, 0, 0, 0);
            if (rg_ < M) {
                size_t a = (size_t)rg_ * K + k0 + f * 8;
                vh = *(const int4*)&Ah[a];
                vl = *(const int4*)&Al[a];
            }
            AS[r * 5 + f] = vh;
            AS[64 * 5 + r * 5 + f] = vl;
        }
        {   // stage B: 128 n-rows x 32 k hi+lo from k-tiled layout (coalesced)
            size_t bbase = (size_t)(k0 >> 5) * (256 * 32) + (size_t)(by * 128) * 32;
            #pragma unroll
            for (int it = 0; it < 2; it++) {
                int id = tid + it * 256;
                int r = id >> 2, f = id & 3;
                size_t a = bbase + (size_t)r * 32 + f * 8;
                BS[r * 5 + f] = *(const int4*)&BgH[a];
                BS[128 * 5 + r * 5 + f] = *(const int4*)&BgL[a];
            }
        }
        __syncthreads();

        const bf16x8* ASv = (const bf16x8*)AS;
        const bf16x8* BSv = (const bf16x8*)BS;
        const int slot = lane >> 4;
        bf16x8 ah[4], al[4];
        #pragma unroll
        for (int mt = 0; mt < 4; mt++) {
            int r = mt * 16 + (lane & 15);
            ah[mt] = ASv[r * 5 + slot];
            al[mt] = ASv[64 * 5 + r * 5 + slot];
        }
        #pragma unroll
        for (int nt = 0; nt < 2; nt++) {
            int rb = (w * 2 + nt) * 16 + (lane & 15);
            bf16x8 bh = BSv[rb * 5 + slot];
            bf16x8 bl = BSv[128 * 5 + rb * 5 + slot];
            #pragma unroll
            for (int mt = 0; mt < 4; mt++) {
                acc[mt][nt] = __builtin_amdgcn_mfma_f32_16x16x32_bf16(ah[mt], bh, acc[mt][nt], 0, 0, 0);
                acc[mt][nt] = __builtin_amdgcn_mfma_f32_16x16x32_bf16(ah[mt], bl, acc[mt][nt], 0, 0, 0);
                acc[mt][nt] = __builtin_amdgcn_mfma_f32_16x16x32_bf16(al[mt], bh, acc[mt][nt], 0, 0, 0);
            }
        }
        __syncthreads();
    }

    // Epilogue. C/D: col=lane&15 within 16-tile, row=(lane>>4)*4+reg.
    const int c15 = lane & 15, lhi = lane >> 4;
    const int hd = by * 4 + w;
    float asw[2], adw[2], bw[2];
    #pragma unroll
    for (int nt = 0; nt < 2; nt++) {
        int col = by * 128 + w * 32 + nt * 16 + c15;
        asw[nt] = att_s[col]; adw[nt] = att_d[col]; bw[nt] = bias[col];
    }
    #pragma unroll
    for (int mt = 0; mt < 4; mt++) {
        #pragma unroll
        for (int rg = 0; rg < 4; rg++) {
            int row = row0 + mt * 16 + lhi * 4 + rg;
            bool ok = row < M;
            float v0 = acc[mt][0][rg] + bw[0], v1 = acc[mt][1][rg] + bw[1];
            if (ok) {
                unsigned short* zp = zb + (size_t)row * DHID + by * 128 + w * 32 + c15;
                zp[0] = f2bf(v0); zp[16] = f2bf(v1);
            }
            float hs = v0 * asw[0] + v1 * asw[1];
            float hdd = v0 * adw[0] + v1 * adw[1];
            #pragma unroll
            for (int off = 1; off < 16; off <<= 1) {
                hs += __shfl_xor(hs, off, 64); hdd += __shfl_xor(hdd, off, 64);
            }
            if (ok && c15 == 0) {
                a_s[row * HEADS + hd] = hs;
                a_d[row * HEADS + hd] = hdd;
            }
        }
    }
}

// ========== score GEMM: bf16 A (relu'd), K=256, score-reduce epilogue =======
__global__ __launch_bounds__(256)
void score_gemm(const unsigned short* __restrict__ Ab, const unsigned short* __restrict__ BgH,
                const float* __restrict__ bias, const float* __restrict__ q,
                float* __restrict__ score, int M)
{
    __shared__ int4 AS[64 * 5];
    __shared__ int4 BS[256 * 5];
    __shared__ float red[4][2];
    const int row0 = blockIdx.x * 64;
    const int tid = threadIdx.x, lane = tid & 63, w = tid >> 6;

    f32x4 acc[4][4];
    const f32x4 zero4 = {0.f, 0.f, 0.f, 0.f};
    #pragma unroll
    for (int i = 0; i < 4; i++)
        #pragma unroll
        for (int j = 0; j < 4; j++) acc[i][j] = zero4;

    for (int k0 = 0; k0 < 256; k0 += 32) {
        {   // stage A: bf16 copy + relu bit-trick
            int r = tid >> 2, f = tid & 3;
            union { int4 v; unsigned short u[8]; } t;
            t.v = *(const int4*)&Ab[(size_t)(row0 + r) * DHID + k0 + f * 8];
            #pragma unroll
            for (int j = 0; j < 8; j++) if (t.u[j] & 0x8000) t.u[j] = 0;
            AS[r * 5 + f] = t.v;
        }
        {   // stage B: k-tile [256][32] hi
            size_t bbase = (size_t)(k0 >> 5) * (256 * 32);
            #pragma unroll
            for (int it = 0; it < 4; it++) {
                int id = tid + it * 256;
                BS[(id >> 2) * 5 + (id & 3)] = *(const int4*)&BgH[bbase + (size_t)id * 8];
            }
        }
        __syncthreads();

        const bf16x8* ASv = (const bf16x8*)AS;
        const bf16x8* BSv = (const bf16x8*)BS;
        const int slot = lane >> 4;
        bf16x8 ah[4];
        #pragma unroll
        for (int mt = 0; mt < 4; mt++) ah[mt] = ASv[(mt * 16 + (lane & 15)) * 5 + slot];
        #pragma unroll
        for (int nt = 0; nt < 4; nt++) {
            bf16x8 bh = BSv[((w * 4 + nt) * 16 + (lane & 15)) * 5 + slot];
            #pragma unroll
            for (int mt = 0; mt < 4; mt++)
                acc[mt][nt] = __builtin_amdgcn_mfma_f32_16x16x32_bf16(ah[mt], bh, acc[mt][nt], 0, 0, 0);
        }
        __syncthreads();
    }

    const int pbase = row0 / N_NODES;
    const int rowSplit = (pbase + 1) * N_NODES;
    float l0 = 0.f, l1 = 0.f;
    #pragma unroll
    for (int nt = 0; nt < 4; nt++) {
        int col = (w * 4 + nt) * 16 + (lane & 15);
        float qc = q[col], bc = bias[col];
        #pragma unroll
        for (int mt = 0; mt < 4; mt++)
            #pragma unroll
            for (int rg = 0; rg < 4; rg++) {
                int row = row0 + mt * 16 + (lane >> 4) * 4 + rg;
                float v = qc * fast_tanh(acc[mt][nt][rg] + bc);
                if (row >= rowSplit) l1 += v; else l0 += v;
            }
    }
    #pragma unroll
    for (int off = 32; off > 0; off >>= 1) {
        l0 += __shfl_down(l0, off, 64);
        l1 += __shfl_down(l1, off, 64);
    }
    if (lane == 0) { red[w][0] = l0; red[w][1] = l1; }
    __syncthreads();
    if (tid == 0)
        atomicAdd(score + pbase, red[0][0] + red[1][0] + red[2][0] + red[3][0]);
    if (tid == 1 && pbase + 1 < P_TYPES)
        atomicAdd(score + pbase + 1, red[0][1] + red[1][1] + red[2][1] + red[3][1]);
}

// ================= scan: gHist -> chunkOff (2.56M entries) ==================
__global__ __launch_bounds__(1024)
void scan_block(const int* __restrict__ counts, int* __restrict__ out,
                int* __restrict__ blockSum, int total)
{
    __shared__ int wsum[16];
    int tid = threadIdx.x, lane = tid & 63, w = tid >> 6;
    int i = blockIdx.x * 1024 + tid;
    int v = (i < total) ? counts[i] : 0;
    int incl = v;
    #pragma unroll
    for (int off = 1; off < 64; off <<= 1) {
        int t = __shfl_up(incl, off, 64);
        if (lane >= off) incl += t;
    }
    if (lane == 63) wsum[w] = incl;
    __syncthreads();
    if (w == 0) {
        int s = (lane < 16) ? wsum[lane] : 0;
        #pragma unroll
        for (int off = 1; off < 16; off <<= 1) {
            int t = __shfl_up(s, off, 64);
            if (lane >= off) s += t;
        }
        if (lane < 16) wsum[lane] = s;
    }
    __syncthreads();
    int waveoff = w ? wsum[w - 1] : 0;
    if (i < total) out[i] = waveoff + incl - v;
    if (tid == 1023 && blockSum) blockSum[blockIdx.x] = wsum[15];
}

// single-block in-place exclusive scan with carry
__global__ __launch_bounds__(1024)
void scan_mid(int* __restrict__ data, int total)
{
    __shared__ int wsum[16];
    __shared__ int carry_s;
    int tid = threadIdx.x, lane = tid & 63, w = tid >> 6;
    if (tid == 0) carry_s = 0;
    __syncthreads();
    for (int base = 0; base < total; base += 1024) {
        int i = base + tid;
        int v = (i < total) ? data[i] : 0;
        int incl = v;
        #pragma unroll
        for (int off = 1; off < 64; off <<= 1) {
            int t = __shfl_up(incl, off, 64);
            if (lane >= off) incl += t;
        }
        if (lane == 63) wsum[w] = incl;
        __syncthreads();
        if (w == 0) {
            int s = (lane < 16) ? wsum[lane] : 0;
            #pragma unroll
            for (int off = 1; off < 16; off <<= 1) {
                int t = __shfl_up(s, off, 64);
                if (lane >= off) s += t;
            }
            if (lane < 16) wsum[lane] = s;
        }
        __syncthreads();
        int waveoff = w ? wsum[w - 1] : 0;
        int carry = carry_s;
        if (i < total) data[i] = carry + waveoff + incl - v;
        __syncthreads();
        if (tid == 1023) carry_s = carry + wsum[15];
        __syncthreads();
    }
}

// add block offsets; extract row_start (every NCHUNK-th) + sentinel
__global__ __launch_bounds__(1024)
void scan_add(int* __restrict__ chunkOff, const int* __restrict__ blockOff,
              int* __restrict__ row_start, int total)
{
    int i = blockIdx.x * 1024 + threadIdx.x;
    if (i == 0) row_start[PN_TOT] = PE_TOT;
    if (i < total) {
        int v = chunkOff[i] + blockOff[blockIdx.x];
        chunkOff[i] = v;
        if ((i & (NCHUNK - 1)) == 0) row_start[i / NCHUNK] = v;
    }
}

// ------- CSR gather: 1 wave/segment, 8 edges in flight, packed bf16 unpack --
__global__ __launch_bounds__(256)
void gather_kernel(const int* __restrict__ row_start, const int* __restrict__ csr_src,
                   const float* __restrict__ a_src, const float* __restrict__ a_dst,
                   const unsigned short* __restrict__ zb, unsigned short* __restrict__ outsb)
{
    int seg = blockIdx.x * 4 + (threadIdx.x >> 6);      // p*N + dst (grid exact)
    int lane = threadIdx.x & 63;
    int sub = lane >> 5, cl = lane & 31;
    int h = cl >> 2;
    int dst = seg % N_NODES;
    float ad = a_dst[dst * HEADS + h];
    int start = row_start[seg], end = row_start[seg + 1];

    float acc[8] = {};
    float den = 0.f;
    int i = start + sub;
    for (; i + 6 < end; i += 8) {                       // 4 edges per half-wave in flight
        int s0 = csr_src[i];
        int s1 = csr_src[i + 2];
        int s2 = csr_src[i + 4];
        int s3 = csr_src[i + 6];
        float g0 = a_src[s0 * HEADS + h];
        float g1 = a_src[s1 * HEADS + h];
        float g2 = a_src[s2 * HEADS + h];
        float g3 = a_src[s3 * HEADS + h];
        uint4 z0 = *(const uint4*)(zb + (size_t)s0 * DHID + cl * 8);
        uint4 z1 = *(const uint4*)(zb + (size_t)s1 * DHID + cl * 8);
        uint4 z2 = *(const uint4*)(zb + (size_t)s2 * DHID + cl * 8);
        uint4 z3 = *(const uint4*)(zb + (size_t)s3 * DHID + cl * 8);
        float e0 = g0 + ad; e0 = e0 > 0.f ? e0 : NEG_SLOPE * e0;
        float e1 = g1 + ad; e1 = e1 > 0.f ? e1 : NEG_SLOPE * e1;
        float e2 = g2 + ad; e2 = e2 > 0.f ? e2 : NEG_SLOPE * e2;
        float e3 = g3 + ad; e3 = e3 > 0.f ? e3 : NEG_SLOPE * e3;
        float w0 = __expf(e0), w1 = __expf(e1), w2 = __expf(e2), w3 = __expf(e3);
        acc[0] += w0 * u2f(z0.x << 16); acc[1] += w0 * u2f(z0.x & 0xffff0000u);
        acc[2] += w0 * u2f(z0.y << 16); acc[3] += w0 * u2f(z0.y & 0xffff0000u);
        acc[4] += w0 * u2f(z0.z << 16); acc[5] += w0 * u2f(z0.z & 0xffff0000u);
        acc[6] += w0 * u2f(z0.w << 16); acc[7] += w0 * u2f(z0.w & 0xffff0000u);
        acc[0] += w1 * u2f(z1.x << 16); acc[1] += w1 * u2f(z1.x & 0xffff0000u);
        acc[2] += w1 * u2f(z1.y << 16); acc[3] += w1 * u2f(z1.y & 0xffff0000u);
        acc[4] += w1 * u2f(z1.z << 16); acc[5] += w1 * u2f(z1.z & 0xffff0000u);
        acc[6] += w1 * u2f(z1.w << 16); acc[7] += w1 * u2f(z1.w & 0xffff0000u);
        acc[0] += w2 * u2f(z2.x << 16); acc[1] += w2 * u2f(z2.x & 0xffff0000u);
        acc[2] += w2 * u2f(z2.y << 16); acc[3] += w2 * u2f(z2.y & 0xffff0000u);
        acc[4] += w2 * u2f(z2.z << 16); acc[5] += w2 * u2f(z2.z & 0xffff0000u);
        acc[6] += w2 * u2f(z2.w << 16); acc[7] += w2 * u2f(z2.w & 0xffff0000u);
        acc[0] += w3 * u2f(z3.x << 16); acc[1] += w3 * u2f(z3.x & 0xffff0000u);
        acc[2] += w3 * u2f(z3.y << 16); acc[3] += w3 * u2f(z3.y & 0xffff0000u);
        acc[4] += w3 * u2f(z3.z << 16); acc[5] += w3 * u2f(z3.z & 0xffff0000u);
        acc[6] += w3 * u2f(z3.w << 16); acc[7] += w3 * u2f(z3.w & 0xffff0000u);
        den += (w0 + w1) + (w2 + w3);
    }
    for (; i < end; i += 2) {
        int s0 = csr_src[i];
        float g0 = a_src[s0 * HEADS + h];
        uint4 z0 = *(const uint4*)(zb + (size_t)s0 * DHID + cl * 8);
        float e0 = g0 + ad; e0 = e0 > 0.f ? e0 : NEG_SLOPE * e0;
        float w0 = __expf(e0);
        acc[0] += w0 * u2f(z0.x << 16); acc[1] += w0 * u2f(z0.x & 0xffff0000u);
        acc[2] += w0 * u2f(z0.y << 16); acc[3] += w0 * u2f(z0.y & 0xffff0000u);
        acc[4] += w0 * u2f(z0.z << 16); acc[5] += w0 * u2f(z0.z & 0xffff0000u);
        acc[6] += w0 * u2f(z0.w << 16); acc[7] += w0 * u2f(z0.w & 0xffff0000u);
        den += w0;
    }
    den += __shfl_xor(den, 32, 64);
    #pragma unroll
    for (int j = 0; j < 8; j++) acc[j] += __shfl_xor(acc[j], 32, 64);
    if (sub == 0) {
        float inv = den > 0.f ? 1.0f / den : 0.f;
        ushort8 o;
        #pragma unroll
        for (int j = 0; j < 8; j++) o[j] = f2bf(acc[j] * inv);
        *(ushort8*)(outsb + (size_t)seg * DHID + cl * 8) = o;
    }
}

// -------- weighted sum over types, fused beta softmax (+relu, opt elu) ------
// OUTMODE 0: fused final classifier -> out f32 [N,16] (block owns 8 rows).
// OUTMODE 1: write bf16 hi/lo (input for proj2).
template<int OUTMODE, bool ELU>
__global__ __launch_bounds__(256)
void wsum_kernel(const unsigned short* __restrict__ outsb, const float* __restrict__ score,
                 unsigned short* __restrict__ hh, unsigned short* __restrict__ hl,
                 const float* __restrict__ Wo, const float* __restrict__ bo,
                 float* __restrict__ out)
{
    __shared__ float hblk[8][256];                      // only used by OUTMODE 0
    int idx = blockIdx.x * 256 + threadIdx.x;           // ushort8 index into [N,256]
    float s0 = score[0], s1 = score[1], s2 = score[2], s3 = score[3];
    float m = fmaxf(fmaxf(s0, s1), fmaxf(s2, s3));
    float b[4];
    b[0] = __expf((s0 - m) * (1.f / N_NODES));
    b[1] = __expf((s1 - m) * (1.f / N_NODES));
    b[2] = __expf((s2 - m) * (1.f / N_NODES));
    b[3] = __expf((s3 - m) * (1.f / N_NODES));
    float dinv = 1.f / (b[0] + b[1] + b[2] + b[3]);
    b[0] *= dinv; b[1] *= dinv; b[2] *= dinv; b[3] *= dinv;

    const size_t stride = (size_t)N_NODES * DHID / 8;
    const ushort8* o = (const ushort8*)outsb;
    float r[8] = {};
    #pragma unroll
    for (int p = 0; p < 4; p++) {
        ushort8 v = o[idx + p * stride];
        #pragma unroll
        for (int j = 0; j < 8; j++) r[j] += b[p] * fmaxf(bf2f(v[j]), 0.f);
    }
    if (ELU) {
        #pragma unroll
        for (int j = 0; j < 8; j++) r[j] = r[j] > 0.f ? r[j] : expm1f(r[j]);
    }
    if (OUTMODE == 1) {
        ushort8 vh, vl;
        #pragma unroll
        for (int j = 0; j < 8; j++) {
            vh[j] = f2bf(r[j]);
            vl[j] = f2bf(r[j] - bf2f(vh[j]));
        }
        ((ushort8*)hh)[idx] = vh;
        ((ushort8*)hl)[idx] = vl;
    } else {
        // stage this block's 8 rows, then 128 threads do [8x256]@[256x16]+bo
        int row_l = threadIdx.x >> 5, u = threadIdx.x & 31;
        #pragma unroll
        for (int j = 0; j < 8; j++) hblk[row_l][u * 8 + j] = r[j];
        __syncthreads();
        int j = threadIdx.x;
        if (j < 8 * NCLASSES) {
            int rl = j >> 4, c = j & 15;
            float accv = bo[c];
            const float* hr = hblk[rl];
            #pragma unroll 8
            for (int k = 0; k < DHID; k++) accv = fmaf(hr[k], Wo[k * NCLASSES + c], accv);
            out[(size_t)(blockIdx.x * 8 + rl) * NCLASSES + c] = accv;
        }
    }
}

extern "C" void kernel_launch(void* const* d_in, const int* in_sizes, int n_in,
                              void* d_out, int out_size, void* d_ws, size_t ws_size,
                              hipStream_t stream)
{
    const float* x   = (const float*)d_in[0];
    const int*  esrc = (const int*)d_in[1];
    const int*  edst = (const int*)d_in[2];
    const float* Wp1 = (const float*)d_in[3];
    const float* bp1 = (const float*)d_in[4];
    const float* as1 = (const float*)d_in[5];
    const float* ad1 = (const float*)d_in[6];
    const float* Wk1 = (const float*)d_in[7];
    const float* bk1 = (const float*)d_in[8];
    const float* q1  = (const float*)d_in[9];
    const float* Wp2 = (const float*)d_in[10];
    const float* bp2 = (const float*)d_in[11];
    const float* as2 = (const float*)d_in[12];
    const float* ad2 = (const float*)d_in[13];
    const float* Wk2 = (const float*)d_in[14];
    const float* bk2 = (const float*)d_in[15];
    const float* q2  = (const float*)d_in[16];
    const float* Wo  = (const float*)d_in[17];
    const float* bo  = (const float*)d_in[18];
    float* out = (float*)d_out;

    // workspace layout (byte offsets, all 16B-aligned)
    char* wsb = (char*)d_ws;
    int* gHist    = (int*)wsb;                                    // 10,240,000
    int* chunkOff = (int*)(wsb + 10240000);                       // 10,240,000
    float* a_s   = (float*)(wsb + 20480000);                      //    640,000
    float* a_d   = (float*)(wsb + 21120000);                      //    640,000
    float* score = (float*)(wsb + 21760000);                      //         32
    unsigned short* zb      = (unsigned short*)(wsb + 21760032);  // 10,240,000
    unsigned short* outsb   = (unsigned short*)(wsb + 32000032);  // 40,960,000
    unsigned short* x_hi    = (unsigned short*)(wsb + 72960032);  // 20,480,000
    unsigned short* x_lo    = (unsigned short*)(wsb + 93440032);  // 20,480,000
    unsigned short* h_hi    = (unsigned short*)(wsb + 113920032); // 10,240,000
    unsigned short* h_lo    = (unsigned short*)(wsb + 124160032); // 10,240,000
    int* rank = (int*)h_hi;   // aliases h_hi: rank lives prep->fill(L1), h_hi wsum(L1)->proj2
    unsigned short* Wp1t_hi = (unsigned short*)(wsb + 134400032); //    262,144
    unsigned short* Wp1t_lo = (unsigned short*)(wsb + 134662176);
    unsigned short* Wp2t_hi = (unsigned short*)(wsb + 134924320); //    131,072
    unsigned short* Wp2t_lo = (unsigned short*)(wsb + 135055392);
    unsigned short* Wk1t_hi = (unsigned short*)(wsb + 135186464);
    unsigned short* Wk2t_hi = (unsigned short*)(wsb + 135317536);
    int* row_start = (int*)(wsb + 135448608);                     //    320,016
    int* blockSum  = (int*)(wsb + 135768624);                     //     10,000
    int* csr_src   = (int*)(wsb + 136089648);                     //  5,120,000

    const int SCAN_TOT = PN_TOT * NCHUNK;        // 2,560,000
    const int NBS = SCAN_TOT / 1024;             // 2500 (exact)

    // ---- prep: {LDS-hist+rank || convert_x || convert_weights} ----
    prep_kernel<<<11408, 256, 0, stream>>>(x, x_hi, x_lo, Wp1, Wp2, Wk1, Wk2,
        Wp1t_hi, Wp1t_lo, Wp2t_hi, Wp2t_lo, Wk1t_hi, Wk2t_hi, score,
        edst, gHist, rank);

    // ---- scan: gHist -> chunkOff (exclusive) + row_start extraction ----
    scan_block<<<NBS, 1024, 0, stream>>>(gHist, chunkOff, blockSum, SCAN_TOT);
    scan_mid<<<1, 1024, 0, stream>>>(blockSum, NBS);
    scan_add<<<NBS, 1024, 0, stream>>>(chunkOff, blockSum, row_start, SCAN_TOT);

    const int PROJ_BLOCKS = 626;                 // 313 x 2
    const int FILL_BLOCKS = PE_TOT / 512;        // 2500 light blocks (exact)
    const int gw = N_NODES * DHID / 8 / 256;     // 2500 blocks, 8 rows each

    // ---- layer 1 (CSR fill rides along with proj1) ----
    proj_fill<<<PROJ_BLOCKS + FILL_BLOCKS, 256, 0, stream>>>(
        x_hi, x_lo, Wp1t_hi, Wp1t_lo, bp1, as1, ad1, zb, a_s, a_d, N_NODES, 512,
        PROJ_BLOCKS, chunkOff, rank, edst, esrc, csr_src);
    gather_kernel<<<PN_TOT / 4, 256, 0, stream>>>(row_start, csr_src, a_s, a_d, zb, outsb);
    score_gemm<<<PN_TOT / 64, 256, 0, stream>>>(outsb, Wk1t_hi, bk1, q1, score, PN_TOT);
    wsum_kernel<1, true><<<gw, 256, 0, stream>>>(outsb, score, h_hi, h_lo,
                                                 nullptr, nullptr, nullptr);

    // ---- layer 2 ----
    proj_fill<<<PROJ_BLOCKS, 256, 0, stream>>>(
        h_hi, h_lo, Wp2t_hi, Wp2t_lo, bp2, as2, ad2, zb, a_s, a_d, N_NODES, 256,
        PROJ_BLOCKS, chunkOff, rank, edst, esrc, csr_src);
    gather_kernel<<<PN_TOT / 4, 256, 0, stream>>>(row_start, csr_src, a_s, a_d, zb, outsb);
    score_gemm<<<PN_TOT / 64, 256, 0, stream>>>(outsb, Wk2t_hi, bk2, q2, score + 4, PN_TOT);
    wsum_kernel<0, false><<<gw, 256, 0, stream>>>(outsb, score + 4, nullptr, nullptr,
                                                  Wo, bo, out);
}